// Round 11
// baseline (415.773 us; speedup 1.0000x reference)
//
#include <hip/hip_runtime.h>
#include <math.h>

#define N_NODES 50000
#define N_EDGES 800000
#define DIM_IN 64
#define DIM_HID 128
#define DIM_OUT 64
#define WROW 128                // bf16 per weight row: 256B

typedef __attribute__((ext_vector_type(8))) short short8;   // 8 bf16 (4 VGPRs)
typedef __attribute__((ext_vector_type(4))) float f32x4;    // MFMA accumulator

union U8 { uint4 u; short8 s; };

// RTNE float->bf16 (inputs finite) -- software path, used only in weight prep
__device__ __forceinline__ unsigned short f2bf(float f) {
    unsigned u = __float_as_uint(f);
    return (unsigned short)((u + 0x7fffu + ((u >> 16) & 1u)) >> 16);
}

// gfx950 has NO cvt_pk_bf16 builtin (learn_hip m240). Single VOP3 via asm.
__device__ __forceinline__ unsigned cvt_pk_bf16(float a, float b) {
    unsigned d;
    asm("v_cvt_pk_bf16_f32 %0, %1, %2" : "=v"(d) : "v"(a), "v"(b));
    return d;
}

__device__ __forceinline__ float exp2_fast(float a) {
#if __has_builtin(__builtin_amdgcn_exp2f)
    return __builtin_amdgcn_exp2f(a);
#else
    return __expf(a * 0.69314718f);
#endif
}

// softplus(x) = max(x,0) + log1p(exp(-|x|)); cubic log1p fit, err ~1.5e-3
__device__ __forceinline__ unsigned sp2(float x0, float x1) {
    const float L2E = 1.44269504f;
    float z0 = exp2_fast(-fabsf(x0) * L2E);
    float z1 = exp2_fast(-fabsf(x1) * L2E);
    float p0 = fmaf(fmaf(fmaf(-0.1011458f, z0, 0.2942925f), z0, -0.5f), z0, 1.0f) * z0;
    float p1 = fmaf(fmaf(fmaf(-0.1011458f, z1, 0.2942925f), z1, -0.5f), z1, 1.0f) * z1;
    return cvt_pk_bf16(fmaxf(x0, 0.0f) + p0, fmaxf(x1, 0.0f) + p1);
}

// Prep: convert x to bf16 table (optional) + bf16 W^T [320][128] (layers 1,2
// carry the K-permutation pi for the C-layout->frag renaming).
template <bool DO_XBF>
__global__ void prep_all(const float* __restrict__ x,
                         const float* __restrict__ W0,
                         const float* __restrict__ W1,
                         const float* __restrict__ W2,
                         unsigned short* __restrict__ wt,
                         unsigned short* __restrict__ xbf) {
    int i = blockIdx.x * blockDim.x + threadIdx.x;

    if (DO_XBF && i < (N_NODES * DIM_IN / 4)) {
        float4 v = *((const float4*)x + i);
        uint2 p;
        p.x = cvt_pk_bf16(v.x, v.y);
        p.y = cvt_pk_bf16(v.z, v.w);
        *((uint2*)xbf + i) = p;
    }

    if (i < 320 * WROW) {
        int row = i >> 7, s = i & 127;
        float v;
        int f = ((s >> 5) << 5) | (((s & 7) >> 2) << 4) | (((s >> 3) & 3) << 2) | (s & 3);
        if (row < 128)      v = W0[s * DIM_HID + row];          // layer 0: natural k
        else if (row < 256) v = W1[f * DIM_HID + (row - 128)];  // layer 1: permuted k
        else                v = W2[f * DIM_OUT + (row - 256)];  // layer 2: permuted k
        wt[i] = f2bf(v);
    }
}

// COMPACT-CODE edge-MLP (I-cache round).
// R0-R10 finding: ~206us floor invariant under fetch/atomic/weight/occupancy/
// barrier/vmcnt diets; issue arithmetic accounts for only ~1/3 of measured
// cycles. The untouched shared resource: the 32KB I-cache vs a fully-unrolled
// ~30-60KB body -- every wave refetches the whole body from L2 every tile
// (also explains lockstep R4 beating drifting persistent R9/R10).
// Fix: runtime ti/L loops (#pragma unroll 1), body ~4KB. The d[ti]->hfr
// rename (which forced full unroll: runtime-indexed register arrays spill,
// rule #20) goes through a per-wave 8KB LDS bounce: producer ds_write_b64
// {d0,d1} at runtime-(m,ti) address; consumer re-reads hfr[m][kk] as 8 static
// ds_read_b128 (same-lane identity -> exact rename semantics; pi in weights).
// Weights from global/L1 (R1 proved the weight data-path isn't the binder).
// No barriers (wave-private buffers). (256,4) = 16 waves/CU, 128-reg cap
// (the only never-spilled cap).
template <bool XB>
__global__ __launch_bounds__(256, 4)
void edge_mlp_mfma(const float* __restrict__ x,
                   const unsigned short* __restrict__ xbf,
                   const int* __restrict__ eidx,
                   const unsigned short* __restrict__ wt,
                   const float* __restrict__ b0,
                   const float* __restrict__ b1,
                   const float* __restrict__ b2,
                   float* __restrict__ out) {
    __shared__ unsigned short Hb[4][4096];   // 4 waves x 8KB activation bounce

    const int lane = threadIdx.x & 63;
    const int w    = threadIdx.x >> 6;       // 0..3
    const int l16  = lane & 15;
    const int q    = lane >> 4;
    const int e0   = blockIdx.x * 128 + w * 32;   // this wave's 32 edges

    unsigned short* hb = Hb[w];
    const int lslot = (q * 16 + l16) * 8;    // ushort offset of this lane's 16B slot

    // ---- gather: layer-0 B-frags B(k=kk*32+q*8+j, edge=m*16+l16) ----
    int nodeR[2], nodeC[2];
#pragma unroll
    for (int m = 0; m < 2; ++m) {
        nodeR[m] = eidx[e0 + m * 16 + l16];
        nodeC[m] = eidx[N_EDGES + e0 + m * 16 + l16];
    }
    int ns[8];
#pragma unroll
    for (int m = 0; m < 2; ++m)
#pragma unroll
        for (int r = 0; r < 4; ++r)
            ns[m * 4 + r] = eidx[e0 + m * 16 + q * 4 + r];   // L1-hot reload

    short8 hfr[2][4];
#pragma unroll
    for (int m = 0; m < 2; ++m)
#pragma unroll
        for (int kk = 0; kk < 4; ++kk) {
            int node = (kk >= 2) ? nodeC[m] : nodeR[m];
            if (XB) {
                hfr[m][kk] = *(const short8*)(xbf + (size_t)node * DIM_IN + (kk & 1) * 32 + q * 8);
            } else {
                const float* p = x + (size_t)node * DIM_IN + (kk & 1) * 32 + q * 8;
                float4 v0 = *(const float4*)p;
                float4 v1 = *(const float4*)(p + 4);
                U8 t;
                t.u.x = cvt_pk_bf16(v0.x, v0.y);
                t.u.y = cvt_pk_bf16(v0.z, v0.w);
                t.u.z = cvt_pk_bf16(v1.x, v1.y);
                t.u.w = cvt_pk_bf16(v1.z, v1.w);
                hfr[m][kk] = t.s;
            }
        }

    // ---- layers 0,1: H^T = softplus(W^T H^T + b); runtime loops ----
#pragma unroll 1
    for (int L = 0; L < 2; ++L) {
        const float* bias = L ? b1 : b0;
        const unsigned short* Wl = wt + L * 128 * WROW + l16 * WROW + q * 8;

#pragma unroll 1
        for (int ti = 0; ti < 8; ++ti) {
            f32x4 bb = *(const f32x4*)(bias + ti * 16 + q * 4);   // bias on row dim
            f32x4 a0 = bb, a1 = bb;
            const unsigned short* Wp = Wl + ti * 16 * WROW;
            short8 wf[4];
#pragma unroll
            for (int kk = 0; kk < 4; ++kk)
                wf[kk] = *(const short8*)(Wp + kk * 32);
#pragma unroll
            for (int kk = 0; kk < 4; ++kk) {
                a0 = __builtin_amdgcn_mfma_f32_16x16x32_bf16(wf[kk], hfr[0][kk], a0, 0, 0, 0);
                a1 = __builtin_amdgcn_mfma_f32_16x16x32_bf16(wf[kk], hfr[1][kk], a1, 0, 0, 0);
            }
            // softplus + pack; write this ti's 8B to the LDS bounce (runtime addr)
            const int toff = (ti >> 1) * 512 + (ti & 1) * 4 + lslot;
            uint2 p0, p1;
            p0.x = sp2(a0[0], a0[1]);
            p0.y = sp2(a0[2], a0[3]);
            p1.x = sp2(a1[0], a1[1]);
            p1.y = sp2(a1[2], a1[3]);
            *(uint2*)(hb + toff)        = p0;   // m=0
            *(uint2*)(hb + 2048 + toff) = p1;   // m=1
        }

        // reload next-layer frags: 8 static ds_read_b128 (same-lane rename)
#pragma unroll
        for (int m = 0; m < 2; ++m)
#pragma unroll
            for (int kk = 0; kk < 4; ++kk)
                hfr[m][kk] = *(const short8*)(hb + m * 2048 + kk * 512 + lslot);
    }

    // ---- layer 2 (un-flipped): O = H W2 + b2; runtime ti loop ----
#pragma unroll 1
    for (int ti = 0; ti < 4; ++ti) {
        float bv = b2[ti * 16 + l16];                    // bias on col dim
        f32x4 a0 = (f32x4){bv, bv, bv, bv};
        f32x4 a1 = a0;
        const unsigned short* Wp = wt + (256 + ti * 16 + l16) * WROW + q * 8;
        short8 wf[4];
#pragma unroll
        for (int kk = 0; kk < 4; ++kk)
            wf[kk] = *(const short8*)(Wp + kk * 32);
#pragma unroll
        for (int kk = 0; kk < 4; ++kk) {
            a0 = __builtin_amdgcn_mfma_f32_16x16x32_bf16(hfr[0][kk], wf[kk], a0, 0, 0, 0);
            a1 = __builtin_amdgcn_mfma_f32_16x16x32_bf16(hfr[1][kk], wf[kk], a1, 0, 0, 0);
        }
        // atomic burst: quad-uniform node, l16 contiguous -> full 64B sectors
#pragma unroll
        for (int r = 0; r < 4; ++r) {
            atomicAdd(out + (size_t)ns[r] * DIM_OUT + ti * 16 + l16, a0[r]);
            atomicAdd(out + (size_t)ns[4 + r] * DIM_OUT + ti * 16 + l16, a1[r]);
        }
    }
}

extern "C" void kernel_launch(void* const* d_in, const int* in_sizes, int n_in,
                              void* d_out, int out_size, void* d_ws, size_t ws_size,
                              hipStream_t stream) {
    const float* x  = (const float*)d_in[0];
    const int*   ei = (const int*)d_in[1];
    const float* W0 = (const float*)d_in[2];
    const float* b0 = (const float*)d_in[3];
    const float* W1 = (const float*)d_in[4];
    const float* b1 = (const float*)d_in[5];
    const float* W2 = (const float*)d_in[6];
    const float* b2 = (const float*)d_in[7];
    float* out = (float*)d_out;

    unsigned short* wt = (unsigned short*)d_ws;
    const size_t WT_BYTES = (size_t)320 * WROW * sizeof(unsigned short);  // 81920
    unsigned short* xbf = (unsigned short*)((char*)d_ws + WT_BYTES);
    const size_t need = WT_BYTES + (size_t)N_NODES * DIM_IN * sizeof(unsigned short); // ~6.5 MB

    hipMemsetAsync(out, 0, (size_t)N_NODES * DIM_OUT * sizeof(float), stream);

    if (ws_size >= need) {
        prep_all<true><<<(N_NODES * DIM_IN / 4 + 255) / 256, 256, 0, stream>>>(
            x, W0, W1, W2, wt, xbf);
        edge_mlp_mfma<true><<<N_EDGES / 128, 256, 0, stream>>>(
            x, xbf, ei, wt, b0, b1, b2, out);
    } else {
        // fallback: weights-only prep, f32 x gather
        prep_all<false><<<(320 * WROW + 255) / 256, 256, 0, stream>>>(
            x, W0, W1, W2, wt, nullptr);
        edge_mlp_mfma<false><<<N_EDGES / 128, 256, 0, stream>>>(
            x, nullptr, ei, wt, b0, b1, b2, out);
    }
}

// Round 14
// 259.450 us; speedup vs baseline: 1.6025x; 1.6025x over previous
//
#include <hip/hip_runtime.h>
#include <math.h>

#define N_NODES 50000
#define N_EDGES 800000
#define DIM_IN 64
#define DIM_HID 128
#define DIM_OUT 64
#define WROW 128   // bf16 per weight row: 256B exactly (no pad; XOR swizzle handles banks)

typedef __attribute__((ext_vector_type(8))) short short8;   // 8 bf16 (4 VGPRs)
typedef __attribute__((ext_vector_type(4))) float f32x4;    // MFMA accumulator

union U8 { uint4 u; short8 s; };

// RTNE float->bf16 (inputs finite) -- software path, used only in weight prep
__device__ __forceinline__ unsigned short f2bf(float f) {
    unsigned u = __float_as_uint(f);
    return (unsigned short)((u + 0x7fffu + ((u >> 16) & 1u)) >> 16);
}

// gfx950 has NO cvt_pk_bf16 builtin (learn_hip m240). Single VOP3 via asm.
// lo = a, hi = b; RTNE (default round mode) == the software f2bf path.
__device__ __forceinline__ unsigned cvt_pk_bf16(float a, float b) {
    unsigned d;
    asm("v_cvt_pk_bf16_f32 %0, %1, %2" : "=v"(d) : "v"(a), "v"(b));
    return d;
}

__device__ __forceinline__ float exp2_fast(float a) {
#if __has_builtin(__builtin_amdgcn_exp2f)
    return __builtin_amdgcn_exp2f(a);
#else
    return __expf(a * 0.69314718f);
#endif
}

// softplus(x) = max(x,0) + log1p(exp(-|x|)); log1p(z) ~ z*(1 + z*(-0.5 + z*(A + z*B)))
// cubic fit on z in (0,1], max abs err ~1.5e-3 (below bf16 quantization of H)
__device__ __forceinline__ unsigned sp2(float x0, float x1) {
    const float L2E = 1.44269504f;
    float z0 = exp2_fast(-fabsf(x0) * L2E);
    float z1 = exp2_fast(-fabsf(x1) * L2E);
    float p0 = fmaf(fmaf(fmaf(-0.1011458f, z0, 0.2942925f), z0, -0.5f), z0, 1.0f) * z0;
    float p1 = fmaf(fmaf(fmaf(-0.1011458f, z1, 0.2942925f), z1, -0.5f), z1, 1.0f) * z1;
    return cvt_pk_bf16(fmaxf(x0, 0.0f) + p0, fmaxf(x1, 0.0f) + p1);
}

// Prep: convert x to a bf16 table (optional) + build bf16 W^T [320][128] table
// (layers 1,2 carry the K-permutation pi matching the MFMA C-layout -> frag
// renaming). Output zeroing is a separate hipMemsetAsync (DMA path).
template <bool DO_XBF>
__global__ void prep_all(const float* __restrict__ x,
                         const float* __restrict__ W0,
                         const float* __restrict__ W1,
                         const float* __restrict__ W2,
                         unsigned short* __restrict__ wt,
                         unsigned short* __restrict__ xbf) {
    int i = blockIdx.x * blockDim.x + threadIdx.x;

    if (DO_XBF && i < (N_NODES * DIM_IN / 4)) {      // 800000 float4 -> uint2 bf16
        float4 v = *((const float4*)x + i);
        uint2 p;
        p.x = cvt_pk_bf16(v.x, v.y);
        p.y = cvt_pk_bf16(v.z, v.w);
        *((uint2*)xbf + i) = p;
    }

    if (i < 320 * WROW) {                            // 40960 weight elements
        int row = i >> 7, s = i & 127;
        float v;
        int f = ((s >> 5) << 5) | (((s & 7) >> 2) << 4) | (((s >> 3) & 3) << 2) | (s & 3);
        if (row < 128)      v = W0[s * DIM_HID + row];          // layer 0: natural k
        else if (row < 256) v = W1[f * DIM_HID + (row - 128)];  // layer 1: permuted k
        else                v = W2[f * DIM_OUT + (row - 256)];  // layer 2: permuted k
        wt[i] = f2bf(v);
    }
}

// Layers 0,1 flipped: H^T = softplus(W^T H^T + b) via mfma(A=weight, B=activation).
// Layer 2 un-flipped: O = H W2 + b2 via mfma(A=activation, B=weight); C row=edge.
//
// OCCUPANCY, DE-CONFOUNDED (R5-R7 coupled blocks/CU to a register cap and
// spilled; R13 lesson: launch_bounds only needs to NOT constrain): this is
// R7's kernel (16,384B LDS chunks, WROW=128 + XOR swizzle -- numerics passed)
// at the never-spilled (256,4) cap (R4 compiled to VGPR 60 under it). HW
// occupancy = min(VGPR 60 -> 32 waves/CU budget, LDS 16KB -> 10 blocks/CU)
// => up to 8 blocks/CU co-resident, 2x R4's 4, zero spill risk.
// Weight chunks: five 64-row x 256B chunks; L0 = chunks 0,1; L1 = 2,3;
// L2 = 4. XOR slot swizzle: 16B-slot col of row r stored at col^(r&7); read
// lanes (l16,q) at fixed kk hit bank-group (4kk+q)^(l16&7) -> uniform 8
// lanes/group = width-limited minimum. Staging writes: 2 dwords/bank = free.
template <bool XB>
__global__ __launch_bounds__(256, 4)
void edge_mlp_mfma(const float* __restrict__ x,
                   const unsigned short* __restrict__ xbf,
                   const int* __restrict__ eidx,
                   const unsigned short* __restrict__ wt,
                   const float* __restrict__ b0,
                   const float* __restrict__ b1,
                   const float* __restrict__ b2,
                   float* __restrict__ out) {
    __shared__ unsigned short lw[64 * WROW];   // 16,384 B: one 64-row weight chunk

    const int lane = threadIdx.x & 63;
    const int w    = threadIdx.x >> 6;
    const int l16  = lane & 15;
    const int q    = lane >> 4;
    const int sx   = l16 & 7;                  // read-side swizzle key
    const int e0w  = blockIdx.x * 128 + w * 32;   // this wave's 32 edges

    int nodeR[2], nodeC[2];
#pragma unroll
    for (int m = 0; m < 2; ++m) {
        nodeR[m] = eidx[e0w + m * 16 + l16];
        nodeC[m] = eidx[N_EDGES + e0w + m * 16 + l16];
    }

    // layer-2 scatter nodes for this quad's 8 edges (L1-hot reload)
    int ns[8];
#pragma unroll
    for (int m = 0; m < 2; ++m)
#pragma unroll
        for (int r = 0; r < 4; ++r)
            ns[m * 4 + r] = eidx[e0w + m * 16 + q * 4 + r];

    // layer-0 B-frags: B(k=kk*32+q*8+j, edge=m*16+l16) -- issued before the
    // first stage+barrier so gather latency hides under them
    short8 hfr[2][4];
#pragma unroll
    for (int m = 0; m < 2; ++m)
#pragma unroll
        for (int kk = 0; kk < 4; ++kk) {
            int node = (kk >= 2) ? nodeC[m] : nodeR[m];
            if (XB) {
                hfr[m][kk] = *(const short8*)(xbf + (size_t)node * DIM_IN + (kk & 1) * 32 + q * 8);
            } else {
                const float* p = x + (size_t)node * DIM_IN + (kk & 1) * 32 + q * 8;
                float4 v0 = *(const float4*)p;
                float4 v1 = *(const float4*)(p + 4);
                U8 t;
                t.u.x = cvt_pk_bf16(v0.x, v0.y);
                t.u.y = cvt_pk_bf16(v0.z, v0.w);
                t.u.z = cvt_pk_bf16(v1.x, v1.y);
                t.u.w = cvt_pk_bf16(v1.z, v1.w);
                hfr[m][kk] = t.s;
            }
        }

    // stage chunk c (weight rows c*64..c*64+63): 1024 uint4 = 4 exact rounds.
    // LDS slot-swizzled: source 16B-slot col of row goes to col ^ (row&7).
    auto stage = [&](int c) {
        const uint4* src = (const uint4*)(wt + (size_t)c * 64 * WROW);
        uint4* dst = (uint4*)lw;
#pragma unroll
        for (int it = 0; it < 4; ++it) {
            int i = threadIdx.x + it * 256;        // 0..1023
            int row = i >> 4, col = i & 15;
            dst[(row << 4) | (col ^ (row & 7))] = src[i];
        }
    };

    stage(0);
    __syncthreads();

    // ---- layers 0,1: H^T = softplus(W^T H^T + b), weights from LDS chunks ----
#pragma unroll
    for (int L = 0; L < 2; ++L) {
        const float* bias = L ? b1 : b0;
        unsigned d[2][8][2];
#pragma unroll
        for (int half = 0; half < 2; ++half) {
#pragma unroll
            for (int ti = 0; ti < 4; ++ti) {
                const int tiG = half * 4 + ti;
                f32x4 bb = *(const f32x4*)(bias + tiG * 16 + q * 4);  // bias on row dim
                f32x4 a0 = bb, a1 = bb;
                const unsigned short* rowb = lw + (ti * 16 + l16) * WROW;
                short8 wf[4];
#pragma unroll
                for (int kk = 0; kk < 4; ++kk)
                    wf[kk] = *(const short8*)(rowb + ((kk * 4 + q) ^ sx) * 8); // ds_read_b128, swizzled
#pragma unroll
                for (int kk = 0; kk < 4; ++kk) {
                    a0 = __builtin_amdgcn_mfma_f32_16x16x32_bf16(wf[kk], hfr[0][kk], a0, 0, 0, 0);
                    a1 = __builtin_amdgcn_mfma_f32_16x16x32_bf16(wf[kk], hfr[1][kk], a1, 0, 0, 0);
                }
                // per-ti epilogue keeps acc liveness at 8 VGPRs
                d[0][tiG][0] = sp2(a0[0], a0[1]);
                d[0][tiG][1] = sp2(a0[2], a0[3]);
                d[1][tiG][0] = sp2(a1[0], a1[1]);
                d[1][tiG][1] = sp2(a1[2], a1[3]);
            }
            // swap in the next 64-row chunk (the last one is L2's table)
            __syncthreads();                  // all waves done reading lw
            stage(L * 2 + half + 1);
            __syncthreads();
        }
        // next-layer frags: pure register renaming (weights carry pi)
#pragma unroll
        for (int m = 0; m < 2; ++m)
#pragma unroll
            for (int kk = 0; kk < 4; ++kk) {
                U8 t;
                t.u.x = d[m][2 * kk][0];
                t.u.y = d[m][2 * kk][1];
                t.u.z = d[m][2 * kk + 1][0];
                t.u.w = d[m][2 * kk + 1][1];
                hfr[m][kk] = t.s;
            }
    }

    // ---- layer 2 (un-flipped): O = H W2 + b2; lw holds chunk 4 (rows 256..319).
    // All loads complete before any atomic issues (vmcnt is in-order).
    {
        f32x4 acc[4][2];
#pragma unroll
        for (int ti = 0; ti < 4; ++ti) {
            float bv = b2[ti * 16 + l16];                    // bias on col dim
            f32x4 a0 = (f32x4){bv, bv, bv, bv};
            f32x4 a1 = a0;
            const unsigned short* rowb = lw + (ti * 16 + l16) * WROW;
            short8 wf[4];
#pragma unroll
            for (int kk = 0; kk < 4; ++kk)
                wf[kk] = *(const short8*)(rowb + ((kk * 4 + q) ^ sx) * 8);  // ds_read_b128, swizzled
#pragma unroll
            for (int kk = 0; kk < 4; ++kk) {
                a0 = __builtin_amdgcn_mfma_f32_16x16x32_bf16(hfr[0][kk], wf[kk], a0, 0, 0, 0);
                a1 = __builtin_amdgcn_mfma_f32_16x16x32_bf16(hfr[1][kk], wf[kk], a1, 0, 0, 0);
            }
            acc[ti][0] = a0;
            acc[ti][1] = a1;
        }

        // terminal atomic burst: fire-and-forget, nothing waits on the acks.
        // each instruction covers full 64B sectors (quad-uniform node, l16 lanes
        // contiguous), 4 transactions/instr.
#pragma unroll
        for (int ti = 0; ti < 4; ++ti)
#pragma unroll
            for (int r = 0; r < 4; ++r) {
                atomicAdd(out + (size_t)ns[r] * DIM_OUT + ti * 16 + l16, acc[ti][0][r]);
                atomicAdd(out + (size_t)ns[4 + r] * DIM_OUT + ti * 16 + l16, acc[ti][1][r]);
            }
    }
}

extern "C" void kernel_launch(void* const* d_in, const int* in_sizes, int n_in,
                              void* d_out, int out_size, void* d_ws, size_t ws_size,
                              hipStream_t stream) {
    const float* x  = (const float*)d_in[0];
    const int*   ei = (const int*)d_in[1];
    const float* W0 = (const float*)d_in[2];
    const float* b0 = (const float*)d_in[3];
    const float* W1 = (const float*)d_in[4];
    const float* b1 = (const float*)d_in[5];
    const float* W2 = (const float*)d_in[6];
    const float* b2 = (const float*)d_in[7];
    float* out = (float*)d_out;

    unsigned short* wt = (unsigned short*)d_ws;
    const size_t WT_BYTES = (size_t)320 * WROW * sizeof(unsigned short);  // 81920 (256-aligned)
    unsigned short* xbf = (unsigned short*)((char*)d_ws + WT_BYTES);
    const size_t need = WT_BYTES + (size_t)N_NODES * DIM_IN * sizeof(unsigned short); // ~6.5 MB

    hipMemsetAsync(out, 0, (size_t)N_NODES * DIM_OUT * sizeof(float), stream);

    if (ws_size >= need) {
        prep_all<true><<<(N_NODES * DIM_IN / 4 + 255) / 256, 256, 0, stream>>>(
            x, W0, W1, W2, wt, xbf);
        edge_mlp_mfma<true><<<N_EDGES / 128, 256, 0, stream>>>(
            x, xbf, ei, wt, b0, b1, b2, out);
    } else {
        // fallback: weights-only prep, f32 x gather
        prep_all<false><<<(320 * WROW + 255) / 256, 256, 0, stream>>>(
            x, W0, W1, W2, wt, nullptr);
        edge_mlp_mfma<false><<<N_EDGES / 128, 256, 0, stream>>>(
            x, nullptr, ei, wt, b0, b1, b2, out);
    }
}